// Round 5
// baseline (430.679 us; speedup 1.0000x reference)
//
#include <hip/hip_runtime.h>
#include <hip/hip_bf16.h>

// MoE top-2, T=32768 tokens, D=1024, E=8.
// Pipeline: gate(4 tok/wave) -> hist -> scan -> scatter(+inverse map) -> wconv
//           -> grouped GEMM (256^2 tile, 4-phase counted-vmcnt schedule) -> combine.

typedef __attribute__((ext_vector_type(8))) short short8_t;
typedef __attribute__((ext_vector_type(4))) float f32x4_t;

#define GLOAD_LDS16(g, l)                                                                     \
  __builtin_amdgcn_global_load_lds((const __attribute__((address_space(1))) unsigned int*)(g), \
                                   (__attribute__((address_space(3))) unsigned int*)(l), 16, 0, 0)

__device__ __forceinline__ unsigned short f2bf(float f) {
  union { __hip_bfloat16 h; unsigned short u; } c;
  c.h = __float2bfloat16(f);
  return c.u;
}

// ---------------- gate: 4 tokens/wave; fp32 logits, top-2 softmax; x -> bf16 ----------------
__global__ __launch_bounds__(256) void gate_kernel(
    const float* __restrict__ x, const float* __restrict__ gw,
    unsigned short* __restrict__ xb,
    int* __restrict__ tok_e, float* __restrict__ tok_w)
{
  int wid = threadIdx.x >> 6, lane = threadIdx.x & 63;
  int t0 = (blockIdx.x << 4) + (wid << 2);              // 4 tokens per wave
  const float4* g4 = (const float4*)gw;                 // gw is [1024][8] row-major
  float lg[4][8] = {};
  #pragma unroll
  for (int c = 0; c < 4; ++c) {
    int d4 = (c << 6) + lane;                           // float4 index within a row
    float4 ga[4], gb[4];
    #pragma unroll
    for (int j = 0; j < 4; ++j) {
      int d = (d4 << 2) + j;
      ga[j] = g4[d << 1];
      gb[j] = g4[(d << 1) + 1];
    }
    #pragma unroll
    for (int t = 0; t < 4; ++t) {                       // reuse gw regs across 4 tokens
      const float4* x4 = (const float4*)(x + ((size_t)(t0 + t) << 10));
      float4 v = x4[d4];
      unsigned long long pk = (unsigned long long)f2bf(v.x)
                            | ((unsigned long long)f2bf(v.y) << 16)
                            | ((unsigned long long)f2bf(v.z) << 32)
                            | ((unsigned long long)f2bf(v.w) << 48);
      ((unsigned long long*)(xb + ((size_t)(t0 + t) << 10)))[d4] = pk;
      float xs[4] = {v.x, v.y, v.z, v.w};
      #pragma unroll
      for (int j = 0; j < 4; ++j) {
        lg[t][0] += xs[j]*ga[j].x; lg[t][1] += xs[j]*ga[j].y;
        lg[t][2] += xs[j]*ga[j].z; lg[t][3] += xs[j]*ga[j].w;
        lg[t][4] += xs[j]*gb[j].x; lg[t][5] += xs[j]*gb[j].y;
        lg[t][6] += xs[j]*gb[j].z; lg[t][7] += xs[j]*gb[j].w;
      }
    }
  }
  #pragma unroll
  for (int t = 0; t < 4; ++t)
    #pragma unroll
    for (int e = 0; e < 8; ++e) {
      float v = lg[t][e];
      #pragma unroll
      for (int s = 32; s > 0; s >>= 1) v += __shfl_xor(v, s, 64);
      lg[t][e] = v;
    }
  if (lane < 4) {                                       // lane t finalizes token t0+t
    int t = t0 + lane;
    float m0 = lg[lane][0], m1 = -3.4e38f; int e0 = 0, e1 = 0;
    #pragma unroll
    for (int e = 1; e < 8; ++e) {                       // strict '>' matches jax top_k ties
      float v = lg[lane][e];
      if (v > m0) { m1 = m0; e1 = e0; m0 = v; e0 = e; }
      else if (v > m1) { m1 = v; e1 = e; }
    }
    float p1 = 1.0f / (1.0f + expf(m0 - m1));
    float p0 = 1.0f - p1;
    int i0 = t << 1;
    tok_e[i0]   = e0; tok_w[i0]   = p0;
    tok_e[i0+1] = e1; tok_w[i0+1] = p1;
  }
}

// ---------------- hist: per-256-entry chunk, LDS histogram + local rank ----------------
__global__ __launch_bounds__(256) void hist_kernel(
    const int* __restrict__ tok_e, int* __restrict__ tok_r, int* __restrict__ chunkhist)
{
  __shared__ int lh[8];
  if (threadIdx.x < 8) lh[threadIdx.x] = 0;
  __syncthreads();
  int i = (blockIdx.x << 8) + threadIdx.x;
  int e = tok_e[i];
  tok_r[i] = atomicAdd(&lh[e], 1);
  __syncthreads();
  if (threadIdx.x < 8) chunkhist[(blockIdx.x << 3) + threadIdx.x] = lh[threadIdx.x];
}

// ---------------- scan: 8 waves, wave e scans expert e across 256 chunks ----------------
__global__ __launch_bounds__(512) void scan_kernel(
    const int* __restrict__ chunkhist, int* __restrict__ base, int* __restrict__ ctrl)
{
  __shared__ int h[2048];
  __shared__ int bx[2048];
  __shared__ int tot[8], eoff[8];
  for (int i = threadIdx.x; i < 2048; i += 512) h[i] = chunkhist[i];
  __syncthreads();
  int wid = threadIdx.x >> 6, lane = threadIdx.x & 63;
  int running = 0;
  #pragma unroll
  for (int b = 0; b < 4; ++b) {
    int c = (b << 6) + lane;
    int orig = h[(c << 3) + wid];
    int v = orig;
    #pragma unroll
    for (int s = 1; s < 64; s <<= 1) {
      int u = __shfl_up(v, s, 64);
      if (lane >= s) v += u;
    }
    bx[(c << 3) + wid] = running + v - orig;            // exclusive, expert-local
    running += __shfl(v, 63, 64);
  }
  if (lane == 0) tot[wid] = running;
  __syncthreads();
  if (threadIdx.x == 0) {
    int off = 0, boff = 0;
    #pragma unroll
    for (int e = 0; e < 8; ++e) {
      ctrl[e] = tot[e];
      ctrl[8 + e] = off; eoff[e] = off; off += tot[e];
      ctrl[16 + e] = boff; boff += (tot[e] + 255) >> 8;  // 256-row M-groups
    }
    ctrl[24] = boff;
  }
  __syncthreads();
  for (int i = threadIdx.x; i < 2048; i += 512) base[i] = bx[i] + eoff[i & 7];
}

// ---------------- scatter (t,k) -> dense slots + inverse map ----------------
__global__ __launch_bounds__(256) void scatter_kernel(
    const int* __restrict__ tok_e, const int* __restrict__ tok_r, const float* __restrict__ tok_w,
    const int* __restrict__ base, int* __restrict__ slot_token, float* __restrict__ slot_w,
    int* __restrict__ tok_slot)
{
  int i = (blockIdx.x << 8) + threadIdx.x;
  int e = tok_e[i];
  int slot = base[((i >> 8) << 3) + e] + tok_r[i];
  slot_token[slot] = i >> 1;
  slot_w[slot] = tok_w[i];
  tok_slot[i] = slot;
}

// ---------------- expert_w fp32 [e][k][n] -> bf16 transposed Wt[e][n][k] ----------------
__global__ __launch_bounds__(256) void wconv_kernel(const float* __restrict__ w,
                                                    unsigned short* __restrict__ wt)
{
  __shared__ float tile[32][33];
  const float* we = w + ((size_t)blockIdx.z << 20);
  unsigned short* wte = wt + ((size_t)blockIdx.z << 20);
  int k0 = blockIdx.x << 5, n0 = blockIdx.y << 5;
  for (int i = threadIdx.x; i < 1024; i += 256) {
    int k = i >> 5, n = i & 31;
    tile[k][n] = we[(size_t)(k0 + k) * 1024 + n0 + n];
  }
  __syncthreads();
  for (int i = threadIdx.x; i < 1024; i += 256) {
    int n = i >> 5, k = i & 31;
    wte[(size_t)(n0 + n) * 1024 + k0 + k] = f2bf(tile[k][n]);
  }
}

// ---------------- grouped GEMM: 256x256 tile, BK=64, 8 waves (2Mx4N), dbuf LDS ----------
// 4-phase K-tile schedule: raw s_barrier, counted vmcnt (drain only at tile boundary),
// prefetch t+1 during t's ph0/ph1, setprio around MFMA quadrants.
// LDS rows are 128B; slot swizzle: LDS slot s of row r holds global 16B k-block (s ^ (r&7));
// staging pre-swizzles the GLOBAL source, ds_read applies the same XOR (both-sides rule).
__global__ __launch_bounds__(512, 2) void moe_gemm(
    const unsigned short* __restrict__ xb, const unsigned short* __restrict__ wt,
    const float* __restrict__ bias, const int* __restrict__ ctrl,
    const int* __restrict__ slot_token, const float* __restrict__ slot_w,
    float* __restrict__ ybuf, float* __restrict__ out, int total_slots, int use_ybuf)
{
  __shared__ unsigned short Alds[2 * 256 * 64];   // 64 KB: [buf][row 0..255][k 0..63]
  __shared__ unsigned short Blds[2 * 256 * 64];   // 64 KB
  __shared__ int   tokid[256];
  __shared__ float wrow[256];

  // dispatch map: 4 N-blocks of an M-group share one XCD (d&7)
  int d = blockIdx.x;
  int xcd = d & 7, nb = (d >> 3) & 3, gbase = d >> 5;
  int by = (gbase << 3) | xcd;                    // M-group id
  if (by >= ctrl[24]) return;
  int e = 0;
  #pragma unroll
  for (int i = 1; i < 8; ++i) if (by >= ctrl[16 + i]) e = i;
  int mblk = by - ctrl[16 + e];
  int cnt  = ctrl[e];
  int slot0 = ctrl[8 + e] + (mblk << 8);
  int rows_valid = cnt - (mblk << 8); if (rows_valid > 256) rows_valid = 256;

  int tid = threadIdx.x;
  if (tid < 256) {
    int s = slot0 + tid; if (s > total_slots - 1) s = total_slots - 1;
    tokid[tid] = slot_token[s];
    wrow[tid]  = slot_w[s];
  }
  __syncthreads();                                 // prologue only: no loads in flight yet

  int lane = tid & 63, w = tid >> 6;
  int wm = w >> 2, wn = w & 3;                     // wave grid 2M x 4N
  int l15 = lane & 15, hk = lane >> 4;
  int bn0 = nb << 8;
  const unsigned short* wte = wt + ((size_t)e << 20);

  // staging: thread covers LDS rows (j*64 + tid>>3), 16B slot (tid&7); source k-block
  // pre-swizzled by row&7 so a linear GLDS write yields the swizzled layout.
  int rsub = tid >> 3;                             // 0..63
  int kswz = (tid & 7) ^ (rsub & 7);               // 16B slot within 128B k-window
  const unsigned short* As[4];
  const unsigned short* Bs[4];
  #pragma unroll
  for (int j = 0; j < 4; ++j) {
    As[j] = xb  + ((size_t)tokid[(j << 6) + rsub] << 10) + (kswz << 3);
    Bs[j] = wte + ((size_t)(bn0 + (j << 6) + rsub) << 10) + (kswz << 3);
  }

  f32x4_t acc[8][4] = {};
  short8_t aF[4][2], bF[4][2];

// ds_read with matching XOR: row ar, 32-k half kk, 16B sub-slot hk
#define LDSA(ar, kk) (*(const short8_t*)&Alds[tb + ((ar) << 6) + ((((((kk) << 2) + hk)) ^ ((ar) & 7)) << 3)])
#define LDSB(br, kk) (*(const short8_t*)&Blds[tb + ((br) << 6) + ((((((kk) << 2) + hk)) ^ ((br) & 7)) << 3)])
#define QMFMA(MH, NH)                                                                   \
  _Pragma("unroll") for (int mf = 0; mf < 4; ++mf)                                      \
  _Pragma("unroll") for (int nf = 0; nf < 2; ++nf)                                      \
  _Pragma("unroll") for (int kk = 0; kk < 2; ++kk)                                      \
    acc[(MH)*4+mf][(NH)*2+nf] = __builtin_amdgcn_mfma_f32_16x16x32_bf16(                \
        aF[mf][kk], bF[(NH)*2+nf][kk], acc[(MH)*4+mf][(NH)*2+nf], 0, 0, 0);

  // prologue: stage K-tile 0 into buf 0
  #pragma unroll
  for (int j = 0; j < 4; ++j) GLOAD_LDS16(As[j], &Alds[(j << 12) + (w << 9)]);
  #pragma unroll
  for (int j = 0; j < 4; ++j) GLOAD_LDS16(Bs[j], &Blds[(j << 12) + (w << 9)]);
  asm volatile("s_waitcnt vmcnt(0)" ::: "memory");
  __builtin_amdgcn_s_barrier();
  __builtin_amdgcn_sched_barrier(0);

  int tb = 0;
  for (int t = 0; t < 16; ++t) {
    int ntb = tb ^ 16384;                          // other buffer (shorts)
    bool pf = (t < 15);
    int koff = (t + 1) << 6;
    // ---- ph0: read A(mh0)+B(nh0); prefetch next A ----
    #pragma unroll
    for (int mf = 0; mf < 4; ++mf)
      #pragma unroll
      for (int kk = 0; kk < 2; ++kk)
        aF[mf][kk] = LDSA((wm << 7) + (mf << 4) + l15, kk);
    #pragma unroll
    for (int nf = 0; nf < 2; ++nf)
      #pragma unroll
      for (int kk = 0; kk < 2; ++kk)
        bF[nf][kk] = LDSB((wn << 6) + (nf << 4) + l15, kk);
    if (pf) {
      #pragma unroll
      for (int j = 0; j < 4; ++j)
        GLOAD_LDS16(As[j] + koff, &Alds[ntb + (j << 12) + (w << 9)]);
    }
    __builtin_amdgcn_s_barrier();
    __builtin_amdgcn_s_setprio(1);
    QMFMA(0, 0)
    __builtin_amdgcn_s_setprio(0);
    __builtin_amdgcn_s_barrier();
    // ---- ph1: read B(nh1); prefetch next B ----
    #pragma unroll
    for (int nf = 2; nf < 4; ++nf)
      #pragma unroll
      for (int kk = 0; kk < 2; ++kk)
        bF[nf][kk] = LDSB((wn << 6) + (nf << 4) + l15, kk);
    if (pf) {
      #pragma unroll
      for (int j = 0; j < 4; ++j)
        GLOAD_LDS16(Bs[j] + koff, &Blds[ntb + (j << 12) + (w << 9)]);
    }
    __builtin_amdgcn_s_barrier();
    __builtin_amdgcn_s_setprio(1);
    QMFMA(0, 1)
    __builtin_amdgcn_s_setprio(0);
    __builtin_amdgcn_s_barrier();
    // ---- ph2: read A(mh1) ----
    #pragma unroll
    for (int mf = 0; mf < 4; ++mf)
      #pragma unroll
      for (int kk = 0; kk < 2; ++kk)
        aF[mf][kk] = LDSA((wm << 7) + 64 + (mf << 4) + l15, kk);
    __builtin_amdgcn_s_barrier();
    __builtin_amdgcn_s_setprio(1);
    QMFMA(1, 1)
    __builtin_amdgcn_s_setprio(0);
    __builtin_amdgcn_s_barrier();
    // ---- ph3: no reads; tile-boundary drain ----
    __builtin_amdgcn_s_setprio(1);
    QMFMA(1, 0)
    __builtin_amdgcn_s_setprio(0);
    if (pf) asm volatile("s_waitcnt vmcnt(0)" ::: "memory");
    __builtin_amdgcn_s_barrier();
    __builtin_amdgcn_sched_barrier(0);             // pin next tile's ds_reads after barrier
    tb = ntb;
  }
#undef LDSA
#undef LDSB
#undef QMFMA

  const float* be = bias + (e << 10);
  #pragma unroll
  for (int nf = 0; nf < 4; ++nf) {
    int dout = bn0 + (wn << 6) + (nf << 4) + l15;
    float bv = be[dout];
    #pragma unroll
    for (int mf = 0; mf < 8; ++mf) {
      int rbase = (wm << 7) + (mf << 4) + (hk << 2);
      #pragma unroll
      for (int r = 0; r < 4; ++r) {
        int row = rbase + r;
        if (row < rows_valid) {
          float val = wrow[row] * (acc[mf][nf][r] + bv);
          if (use_ybuf) ybuf[((size_t)(slot0 + row) << 10) + dout] = val;
          else atomicAdd(&out[((size_t)tokid[row] << 10) + dout], val);
        }
      }
    }
  }
}

// ---------------- combine: out[t] = ybuf[slot0(t)] + ybuf[slot1(t)] ----------------
__global__ __launch_bounds__(256) void combine_kernel(
    const float* __restrict__ ybuf, const int* __restrict__ tok_slot, float* __restrict__ out)
{
  int t = blockIdx.x;
  int s0 = tok_slot[t << 1], s1 = tok_slot[(t << 1) + 1];
  const float4* y0 = (const float4*)(ybuf + ((size_t)s0 << 10));
  const float4* y1 = (const float4*)(ybuf + ((size_t)s1 << 10));
  float4 a = y0[threadIdx.x], b = y1[threadIdx.x];
  float4 r; r.x = a.x + b.x; r.y = a.y + b.y; r.z = a.z + b.z; r.w = a.w + b.w;
  ((float4*)(out + ((size_t)t << 10)))[threadIdx.x] = r;
}

extern "C" void kernel_launch(void* const* d_in, const int* in_sizes, int n_in,
                              void* d_out, int out_size, void* d_ws, size_t ws_size,
                              hipStream_t stream) {
  (void)n_in;
  const float* x  = (const float*)d_in[0];
  const float* gw = (const float*)d_in[1];
  const float* ew = (const float*)d_in[2];
  const float* eb = (const float*)d_in[3];
  int T  = in_sizes[0] >> 10;   // 32768
  int T2 = T << 1;              // 65536 slots

  // workspace layout
  char* wsb = (char*)d_ws;
  unsigned short* xb = (unsigned short*)wsb;
  size_t off = (size_t)T * 1024 * 2;                    // x bf16: 64 MB
  unsigned short* wt = (unsigned short*)(wsb + off);
  off += (size_t)8 * 1024 * 1024 * 2;                   // Wt bf16: 16 MB
  int* ctrl = (int*)(wsb + off); off += 256;
  int* tok_e = (int*)(wsb + off); off += (size_t)T2 * 4;
  int* tok_r = (int*)(wsb + off); off += (size_t)T2 * 4;
  float* tok_w = (float*)(wsb + off); off += (size_t)T2 * 4;
  int* slot_token = (int*)(wsb + off); off += (size_t)T2 * 4;
  float* slot_w = (float*)(wsb + off); off += (size_t)T2 * 4;
  int* tok_slot = (int*)(wsb + off); off += (size_t)T2 * 4;
  int* chunkhist = (int*)(wsb + off); off += 2048 * 4;
  int* base = (int*)(wsb + off); off += 2048 * 4;
  float* ybuf = (float*)(wsb + off);
  size_t need = off + (size_t)T2 * 1024 * 4;            // +268 MB
  int use_ybuf = (ws_size >= need) ? 1 : 0;

  float* out = (float*)d_out;

  if (!use_ybuf)
    hipMemsetAsync(d_out, 0, (size_t)out_size * sizeof(float), stream);
  gate_kernel<<<T / 16, 256, 0, stream>>>(x, gw, xb, tok_e, tok_w);
  wconv_kernel<<<dim3(32, 32, 8), 256, 0, stream>>>(ew, wt);
  hist_kernel<<<T2 / 256, 256, 0, stream>>>(tok_e, tok_r, chunkhist);
  scan_kernel<<<1, 512, 0, stream>>>(chunkhist, base, ctrl);
  scatter_kernel<<<T2 / 256, 256, 0, stream>>>(tok_e, tok_r, tok_w, base,
                                               slot_token, slot_w, tok_slot);
  // 264 M-groups (upper bound, padded to x8) x 4 N-blocks
  moe_gemm<<<1056, 512, 0, stream>>>(xb, wt, eb, ctrl, slot_token, slot_w,
                                     ybuf, out, T2, use_ybuf);
  if (use_ybuf)
    combine_kernel<<<T, 256, 0, stream>>>(ybuf, tok_slot, out);
}

// Round 6
// 373.879 us; speedup vs baseline: 1.1519x; 1.1519x over previous
//
#include <hip/hip_runtime.h>
#include <hip/hip_bf16.h>

// MoE top-2, T=32768 tokens, D=1024, E=8.
// Pipeline: gate(4 tok/wave) -> hist -> scan -> scatter(+inverse map) -> wconv
//           -> grouped GEMM (256^2, BK=64, counted-vmcnt 4-phase pipeline) -> combine.

typedef __attribute__((ext_vector_type(8))) short short8_t;
typedef __attribute__((ext_vector_type(4))) float f32x4_t;

#define GLOAD_LDS16(g, l)                                                                     \
  __builtin_amdgcn_global_load_lds((const __attribute__((address_space(1))) unsigned int*)(g), \
                                   (__attribute__((address_space(3))) unsigned int*)(l), 16, 0, 0)

__device__ __forceinline__ unsigned short f2bf(float f) {
  union { __hip_bfloat16 h; unsigned short u; } c;
  c.h = __float2bfloat16(f);
  return c.u;
}

// ---------------- gate: 4 tokens/wave; fp32 logits, top-2 softmax; x -> bf16 ----------------
__global__ __launch_bounds__(256) void gate_kernel(
    const float* __restrict__ x, const float* __restrict__ gw,
    unsigned short* __restrict__ xb,
    int* __restrict__ tok_e, float* __restrict__ tok_w)
{
  int wid = threadIdx.x >> 6, lane = threadIdx.x & 63;
  int t0 = (blockIdx.x << 4) + (wid << 2);              // 4 tokens per wave
  const float4* g4 = (const float4*)gw;                 // gw is [1024][8] row-major
  float lg[4][8] = {};
  #pragma unroll
  for (int c = 0; c < 4; ++c) {
    int d4 = (c << 6) + lane;                           // float4 index within a row
    float4 ga[4], gb[4];
    #pragma unroll
    for (int j = 0; j < 4; ++j) {
      int d = (d4 << 2) + j;
      ga[j] = g4[d << 1];
      gb[j] = g4[(d << 1) + 1];
    }
    #pragma unroll
    for (int t = 0; t < 4; ++t) {                       // reuse gw regs across 4 tokens
      const float4* x4 = (const float4*)(x + ((size_t)(t0 + t) << 10));
      float4 v = x4[d4];
      unsigned long long pk = (unsigned long long)f2bf(v.x)
                            | ((unsigned long long)f2bf(v.y) << 16)
                            | ((unsigned long long)f2bf(v.z) << 32)
                            | ((unsigned long long)f2bf(v.w) << 48);
      ((unsigned long long*)(xb + ((size_t)(t0 + t) << 10)))[d4] = pk;
      float xs[4] = {v.x, v.y, v.z, v.w};
      #pragma unroll
      for (int j = 0; j < 4; ++j) {
        lg[t][0] += xs[j]*ga[j].x; lg[t][1] += xs[j]*ga[j].y;
        lg[t][2] += xs[j]*ga[j].z; lg[t][3] += xs[j]*ga[j].w;
        lg[t][4] += xs[j]*gb[j].x; lg[t][5] += xs[j]*gb[j].y;
        lg[t][6] += xs[j]*gb[j].z; lg[t][7] += xs[j]*gb[j].w;
      }
    }
  }
  #pragma unroll
  for (int t = 0; t < 4; ++t)
    #pragma unroll
    for (int e = 0; e < 8; ++e) {
      float v = lg[t][e];
      #pragma unroll
      for (int s = 32; s > 0; s >>= 1) v += __shfl_xor(v, s, 64);
      lg[t][e] = v;
    }
  if (lane < 4) {                                       // lane t finalizes token t0+t
    int t = t0 + lane;
    float m0 = lg[lane][0], m1 = -3.4e38f; int e0 = 0, e1 = 0;
    #pragma unroll
    for (int e = 1; e < 8; ++e) {                       // strict '>' matches jax top_k ties
      float v = lg[lane][e];
      if (v > m0) { m1 = m0; e1 = e0; m0 = v; e0 = e; }
      else if (v > m1) { m1 = v; e1 = e; }
    }
    float p1 = 1.0f / (1.0f + expf(m0 - m1));
    float p0 = 1.0f - p1;
    int i0 = t << 1;
    tok_e[i0]   = e0; tok_w[i0]   = p0;
    tok_e[i0+1] = e1; tok_w[i0+1] = p1;
  }
}

// ---------------- hist: per-256-entry chunk, LDS histogram + local rank ----------------
__global__ __launch_bounds__(256) void hist_kernel(
    const int* __restrict__ tok_e, int* __restrict__ tok_r, int* __restrict__ chunkhist)
{
  __shared__ int lh[8];
  if (threadIdx.x < 8) lh[threadIdx.x] = 0;
  __syncthreads();
  int i = (blockIdx.x << 8) + threadIdx.x;
  int e = tok_e[i];
  tok_r[i] = atomicAdd(&lh[e], 1);
  __syncthreads();
  if (threadIdx.x < 8) chunkhist[(blockIdx.x << 3) + threadIdx.x] = lh[threadIdx.x];
}

// ---------------- scan: 8 waves, wave e scans expert e across 256 chunks ----------------
__global__ __launch_bounds__(512) void scan_kernel(
    const int* __restrict__ chunkhist, int* __restrict__ base, int* __restrict__ ctrl)
{
  __shared__ int h[2048];
  __shared__ int bx[2048];
  __shared__ int tot[8], eoff[8];
  for (int i = threadIdx.x; i < 2048; i += 512) h[i] = chunkhist[i];
  __syncthreads();
  int wid = threadIdx.x >> 6, lane = threadIdx.x & 63;
  int running = 0;
  #pragma unroll
  for (int b = 0; b < 4; ++b) {
    int c = (b << 6) + lane;
    int orig = h[(c << 3) + wid];
    int v = orig;
    #pragma unroll
    for (int s = 1; s < 64; s <<= 1) {
      int u = __shfl_up(v, s, 64);
      if (lane >= s) v += u;
    }
    bx[(c << 3) + wid] = running + v - orig;            // exclusive, expert-local
    running += __shfl(v, 63, 64);
  }
  if (lane == 0) tot[wid] = running;
  __syncthreads();
  if (threadIdx.x == 0) {
    int off = 0, boff = 0;
    #pragma unroll
    for (int e = 0; e < 8; ++e) {
      ctrl[e] = tot[e];
      ctrl[8 + e] = off; eoff[e] = off; off += tot[e];
      ctrl[16 + e] = boff; boff += (tot[e] + 255) >> 8;  // 256-row M-groups
    }
    ctrl[24] = boff;
  }
  __syncthreads();
  for (int i = threadIdx.x; i < 2048; i += 512) base[i] = bx[i] + eoff[i & 7];
}

// ---------------- scatter (t,k) -> dense slots + inverse map ----------------
__global__ __launch_bounds__(256) void scatter_kernel(
    const int* __restrict__ tok_e, const int* __restrict__ tok_r, const float* __restrict__ tok_w,
    const int* __restrict__ base, int* __restrict__ slot_token, float* __restrict__ slot_w,
    int* __restrict__ tok_slot)
{
  int i = (blockIdx.x << 8) + threadIdx.x;
  int e = tok_e[i];
  int slot = base[((i >> 8) << 3) + e] + tok_r[i];
  slot_token[slot] = i >> 1;
  slot_w[slot] = tok_w[i];
  tok_slot[i] = slot;
}

// ---------------- expert_w fp32 [e][k][n] -> bf16 transposed Wt[e][n][k] ----------------
__global__ __launch_bounds__(256) void wconv_kernel(const float* __restrict__ w,
                                                    unsigned short* __restrict__ wt)
{
  __shared__ float tile[32][33];
  const float* we = w + ((size_t)blockIdx.z << 20);
  unsigned short* wte = wt + ((size_t)blockIdx.z << 20);
  int k0 = blockIdx.x << 5, n0 = blockIdx.y << 5;
  for (int i = threadIdx.x; i < 1024; i += 256) {
    int k = i >> 5, n = i & 31;
    tile[k][n] = we[(size_t)(k0 + k) * 1024 + n0 + n];
  }
  __syncthreads();
  for (int i = threadIdx.x; i < 1024; i += 256) {
    int n = i >> 5, k = i & 31;
    wte[(size_t)(n0 + n) * 1024 + k0 + k] = f2bf(tile[k][n]);
  }
}

// ---------------- grouped GEMM: 256x256, BK=64, 8 waves, counted-vmcnt pipeline ----------
// Per K-tile (4 phases): P0 stage A(t+1), vmcnt(4)=wait B(t), bF0, Q00(aN,bF0);
// P1 stage B(t+1), bF1, Q01(aN,bF1); P2 aF1, Q11; P3 vmcnt(4)=wait A(t+1),
// pre-read aN(t+1) from next buffer, Q10. vmcnt never drains to 0 in the loop.
// LDS slot s of row r holds global 16B k-block (s ^ (r&7)); staging pre-swizzles the
// GLOBAL source, ds_read applies the same XOR (both-sides rule).
__global__ __launch_bounds__(512, 2) void moe_gemm(
    const unsigned short* __restrict__ xb, const unsigned short* __restrict__ wt,
    const float* __restrict__ bias, const int* __restrict__ ctrl,
    const int* __restrict__ slot_token, const float* __restrict__ slot_w,
    float* __restrict__ ybuf, float* __restrict__ out, int total_slots, int use_ybuf)
{
  __shared__ unsigned short Alds[2 * 256 * 64];   // 64 KB: [buf][row][k]
  __shared__ unsigned short Blds[2 * 256 * 64];   // 64 KB
  __shared__ int   tokid[256];
  __shared__ float wrow[256];

  // dispatch map: 4 N-blocks of an M-group share one XCD (d&7)
  int d = blockIdx.x;
  int xcd = d & 7, nb = (d >> 3) & 3, gbase = d >> 5;
  int by = (gbase << 3) | xcd;                    // M-group id
  if (by >= ctrl[24]) return;
  int e = 0;
  #pragma unroll
  for (int i = 1; i < 8; ++i) if (by >= ctrl[16 + i]) e = i;
  int mblk = by - ctrl[16 + e];
  int cnt  = ctrl[e];
  int slot0 = ctrl[8 + e] + (mblk << 8);
  int rows_valid = cnt - (mblk << 8); if (rows_valid > 256) rows_valid = 256;

  int tid = threadIdx.x;
  if (tid < 256) {
    int s = slot0 + tid; if (s > total_slots - 1) s = total_slots - 1;
    tokid[tid] = slot_token[s];
    wrow[tid]  = slot_w[s];
  }
  __syncthreads();                                 // prologue only: no loads in flight yet

  int lane = tid & 63, w = tid >> 6;
  int wm = w >> 2, wn = w & 3;                     // wave grid 2M x 4N
  int l15 = lane & 15, hk = lane >> 4;
  int bn0 = nb << 8;
  const unsigned short* wte = wt + ((size_t)e << 20);

  // staging: thread covers LDS row (tid>>3) per quarter j, 16B slot (tid&7);
  // source k-block pre-swizzled by row&7 so linear GLDS dest yields swizzled layout.
  int rsub = tid >> 3;                             // 0..63
  int kswz = (tid & 7) ^ (rsub & 7);
  const unsigned short* As[4];
  const unsigned short* Bs[4];
  #pragma unroll
  for (int j = 0; j < 4; ++j) {
    As[j] = xb  + ((size_t)tokid[(j << 6) + rsub] << 10) + (kswz << 3);
    Bs[j] = wte + ((size_t)(bn0 + (j << 6) + rsub) << 10) + (kswz << 3);
  }

  f32x4_t acc[8][4] = {};
  short8_t aN[4][2], aF1[4][2], bF0[2][2], bF1[2][2];

#define LDSA(base, ar, kk) (*(const short8_t*)&Alds[(base) + ((ar) << 6) + (((((kk) << 2) + hk) ^ ((ar) & 7)) << 3)])
#define LDSB(base, br, kk) (*(const short8_t*)&Blds[(base) + ((br) << 6) + (((((kk) << 2) + hk) ^ ((br) & 7)) << 3)])
#define QUAD(AF, BF, MB, NB)                                                            \
  _Pragma("unroll") for (int mf = 0; mf < 4; ++mf)                                      \
  _Pragma("unroll") for (int nf = 0; nf < 2; ++nf)                                      \
  _Pragma("unroll") for (int kk = 0; kk < 2; ++kk)                                      \
    acc[(MB)*4+mf][(NB)*2+nf] = __builtin_amdgcn_mfma_f32_16x16x32_bf16(                \
        AF[mf][kk], BF[nf][kk], acc[(MB)*4+mf][(NB)*2+nf], 0, 0, 0);

  // prologue: stage tile 0 into buf 0; pre-read aN(mh0)
  #pragma unroll
  for (int j = 0; j < 4; ++j) GLOAD_LDS16(As[j], &Alds[(j << 12) + (w << 9)]);
  #pragma unroll
  for (int j = 0; j < 4; ++j) GLOAD_LDS16(Bs[j], &Blds[(j << 12) + (w << 9)]);
  asm volatile("s_waitcnt vmcnt(4)" ::: "memory");   // A(0) landed (B(0) in flight)
  __builtin_amdgcn_s_barrier();
  #pragma unroll
  for (int mf = 0; mf < 4; ++mf)
    #pragma unroll
    for (int kk = 0; kk < 2; ++kk)
      aN[mf][kk] = LDSA(0, (wm << 7) + (mf << 4) + l15, kk);

  int tb = 0;
  for (int t = 0; t < 15; ++t) {
    int ntb = tb ^ 16384;
    int koff = (t + 1) << 6;
    // ---- P0: stage A(t+1); wait B(t); read bF0; Q00 ----
    #pragma unroll
    for (int j = 0; j < 4; ++j)
      GLOAD_LDS16(As[j] + koff, &Alds[ntb + (j << 12) + (w << 9)]);
    asm volatile("s_waitcnt vmcnt(4)" ::: "memory");
    __builtin_amdgcn_s_barrier();
    #pragma unroll
    for (int nf = 0; nf < 2; ++nf)
      #pragma unroll
      for (int kk = 0; kk < 2; ++kk)
        bF0[nf][kk] = LDSB(tb, (wn << 6) + (nf << 4) + l15, kk);
    __builtin_amdgcn_s_setprio(1);
    QUAD(aN, bF0, 0, 0)
    __builtin_amdgcn_s_setprio(0);
    // ---- P1: stage B(t+1); read bF1; Q01 ----
    #pragma unroll
    for (int j = 0; j < 4; ++j)
      GLOAD_LDS16(Bs[j] + koff, &Blds[ntb + (j << 12) + (w << 9)]);
    __builtin_amdgcn_s_barrier();
    #pragma unroll
    for (int nf = 0; nf < 2; ++nf)
      #pragma unroll
      for (int kk = 0; kk < 2; ++kk)
        bF1[nf][kk] = LDSB(tb, (wn << 6) + ((nf + 2) << 4) + l15, kk);
    __builtin_amdgcn_s_setprio(1);
    QUAD(aN, bF1, 0, 1)
    __builtin_amdgcn_s_setprio(0);
    // ---- P2: read aF1 (mh1); Q11 ----
    __builtin_amdgcn_s_barrier();
    #pragma unroll
    for (int mf = 0; mf < 4; ++mf)
      #pragma unroll
      for (int kk = 0; kk < 2; ++kk)
        aF1[mf][kk] = LDSA(tb, (wm << 7) + 64 + (mf << 4) + l15, kk);
    __builtin_amdgcn_s_setprio(1);
    QUAD(aF1, bF1, 1, 1)
    __builtin_amdgcn_s_setprio(0);
    // ---- P3: wait A(t+1); pre-read aN from next buffer; Q10 ----
    asm volatile("s_waitcnt vmcnt(4)" ::: "memory");
    __builtin_amdgcn_s_barrier();
    #pragma unroll
    for (int mf = 0; mf < 4; ++mf)
      #pragma unroll
      for (int kk = 0; kk < 2; ++kk)
        aN[mf][kk] = LDSA(ntb, (wm << 7) + (mf << 4) + l15, kk);
    __builtin_amdgcn_s_setprio(1);
    QUAD(aF1, bF0, 1, 0)
    __builtin_amdgcn_s_setprio(0);
    tb = ntb;
  }
  // ---- peeled tile 15: drain remaining B(15); no prefetch ----
  asm volatile("s_waitcnt vmcnt(0)" ::: "memory");
  __builtin_amdgcn_s_barrier();
  #pragma unroll
  for (int nf = 0; nf < 2; ++nf)
    #pragma unroll
    for (int kk = 0; kk < 2; ++kk) {
      bF0[nf][kk] = LDSB(tb, (wn << 6) + (nf << 4) + l15, kk);
      bF1[nf][kk] = LDSB(tb, (wn << 6) + ((nf + 2) << 4) + l15, kk);
    }
  #pragma unroll
  for (int mf = 0; mf < 4; ++mf)
    #pragma unroll
    for (int kk = 0; kk < 2; ++kk)
      aF1[mf][kk] = LDSA(tb, (wm << 7) + 64 + (mf << 4) + l15, kk);
  __builtin_amdgcn_s_setprio(1);
  QUAD(aN, bF0, 0, 0)
  QUAD(aN, bF1, 0, 1)
  QUAD(aF1, bF1, 1, 1)
  QUAD(aF1, bF0, 1, 0)
  __builtin_amdgcn_s_setprio(0);
#undef LDSA
#undef LDSB
#undef QUAD

  const float* be = bias + (e << 10);
  float bv[4];
  #pragma unroll
  for (int nf = 0; nf < 4; ++nf) bv[nf] = be[bn0 + (wn << 6) + (nf << 4) + l15];
  #pragma unroll
  for (int mf = 0; mf < 8; ++mf) {
    int rbase = (wm << 7) + (mf << 4) + (hk << 2);
    #pragma unroll
    for (int r = 0; r < 4; ++r) {
      int row = rbase + r;
      if (row < rows_valid) {
        float wv = wrow[row];
        if (use_ybuf) {
          size_t obase = ((size_t)(slot0 + row) << 10);
          #pragma unroll
          for (int nf = 0; nf < 4; ++nf) {        // 4 back-to-back 64B stores per 256B line
            int dout = bn0 + (wn << 6) + (nf << 4) + l15;
            ybuf[obase + dout] = wv * (acc[mf][nf][r] + bv[nf]);
          }
        } else {
          size_t obase = ((size_t)tokid[row] << 10);
          #pragma unroll
          for (int nf = 0; nf < 4; ++nf) {
            int dout = bn0 + (wn << 6) + (nf << 4) + l15;
            atomicAdd(&out[obase + dout], wv * (acc[mf][nf][r] + bv[nf]));
          }
        }
      }
    }
  }
}

// ---------------- combine: out[t] = ybuf[slot0(t)] + ybuf[slot1(t)] ----------------
__global__ __launch_bounds__(256) void combine_kernel(
    const float* __restrict__ ybuf, const int* __restrict__ tok_slot, float* __restrict__ out)
{
  int t = blockIdx.x;
  int s0 = tok_slot[t << 1], s1 = tok_slot[(t << 1) + 1];
  const float4* y0 = (const float4*)(ybuf + ((size_t)s0 << 10));
  const float4* y1 = (const float4*)(ybuf + ((size_t)s1 << 10));
  float4 a = y0[threadIdx.x], b = y1[threadIdx.x];
  float4 r; r.x = a.x + b.x; r.y = a.y + b.y; r.z = a.z + b.z; r.w = a.w + b.w;
  ((float4*)(out + ((size_t)t << 10)))[threadIdx.x] = r;
}

extern "C" void kernel_launch(void* const* d_in, const int* in_sizes, int n_in,
                              void* d_out, int out_size, void* d_ws, size_t ws_size,
                              hipStream_t stream) {
  (void)n_in;
  const float* x  = (const float*)d_in[0];
  const float* gw = (const float*)d_in[1];
  const float* ew = (const float*)d_in[2];
  const float* eb = (const float*)d_in[3];
  int T  = in_sizes[0] >> 10;   // 32768
  int T2 = T << 1;              // 65536 slots

  // workspace layout
  char* wsb = (char*)d_ws;
  unsigned short* xb = (unsigned short*)wsb;
  size_t off = (size_t)T * 1024 * 2;                    // x bf16: 64 MB
  unsigned short* wt = (unsigned short*)(wsb + off);
  off += (size_t)8 * 1024 * 1024 * 2;                   // Wt bf16: 16 MB
  int* ctrl = (int*)(wsb + off); off += 256;
  int* tok_e = (int*)(wsb + off); off += (size_t)T2 * 4;
  int* tok_r = (int*)(wsb + off); off += (size_t)T2 * 4;
  float* tok_w = (float*)(wsb + off); off += (size_t)T2 * 4;
  int* slot_token = (int*)(wsb + off); off += (size_t)T2 * 4;
  float* slot_w = (float*)(wsb + off); off += (size_t)T2 * 4;
  int* tok_slot = (int*)(wsb + off); off += (size_t)T2 * 4;
  int* chunkhist = (int*)(wsb + off); off += 2048 * 4;
  int* base = (int*)(wsb + off); off += 2048 * 4;
  float* ybuf = (float*)(wsb + off);
  size_t need = off + (size_t)T2 * 1024 * 4;            // +268 MB
  int use_ybuf = (ws_size >= need) ? 1 : 0;

  float* out = (float*)d_out;

  if (!use_ybuf)
    hipMemsetAsync(d_out, 0, (size_t)out_size * sizeof(float), stream);
  gate_kernel<<<T / 16, 256, 0, stream>>>(x, gw, xb, tok_e, tok_w);
  wconv_kernel<<<dim3(32, 32, 8), 256, 0, stream>>>(ew, wt);
  hist_kernel<<<T2 / 256, 256, 0, stream>>>(tok_e, tok_r, chunkhist);
  scan_kernel<<<1, 512, 0, stream>>>(chunkhist, base, ctrl);
  scatter_kernel<<<T2 / 256, 256, 0, stream>>>(tok_e, tok_r, tok_w, base,
                                               slot_token, slot_w, tok_slot);
  // 264 M-groups (upper bound, padded to x8) x 4 N-blocks
  moe_gemm<<<1056, 512, 0, stream>>>(xb, wt, eb, ctrl, slot_token, slot_w,
                                     ybuf, out, T2, use_ybuf);
  if (use_ybuf)
    combine_kernel<<<T, 256, 0, stream>>>(ybuf, tok_slot, out);
}